// Round 4
// baseline (1921.064 us; speedup 1.0000x reference)
//
#include <hip/hip_runtime.h>

// N=524288 rows, A=256 features, C=19 classes.
#define NROW 524288
#define NA 256
#define NC 19
#define IGN 255
// Per-block accumulator layout: sum[4][NC][64] | sumsq[4][NC][64] | count[NC]
// (j = col%4, l = col/4; col = 4*l + j). Lane l -> bank l%32: conflict-free.
#define SQOFF  (4 * NC * 64)       // 4864
#define CNTOFF (2 * SQOFF)         // 9728
#define NCELL  (2 * SQOFF + NC)    // 9747
#define OUTSTRIDE (2 * NA + 1)     // 513

// ---------------------------------------------------------------------------
// Kernel 1: per-block {sum, sumsq, count} accumulation.
// One wave = one row per step: lane l loads float4 (cols 4l..4l+3), then 8
// fire-and-forget ds_add_f32 atomics (no read-after-write lgkm chains).
// LDS 38988 B -> 4 blocks/CU (16 waves/CU). unroll 8 -> 8 KB VMEM in
// flight/wave = 128 KB/CU >> 9 KB Little's-law need at 24.6 GB/s/CU.
// ---------------------------------------------------------------------------
__global__ __launch_bounds__(256, 4) void k_accum(
    const float* __restrict__ feat, const int* __restrict__ lab,
    float* __restrict__ part, int rpb)
{
    __shared__ float acc[NCELL];
    const int t = threadIdx.x;
    const int wave = t >> 6, lane = t & 63;
    for (int i = t; i < NCELL; i += 256) acc[i] = 0.0f;
    __syncthreads();

    const int r0 = blockIdx.x * rpb;
    const int r1 = min(r0 + rpb, NROW);
    const int nrows = r1 - r0;
    const float4* __restrict__ fg = (const float4*)feat;

    if ((nrows & 3) == 0 && nrows > 0) {
        // Fast path (always taken for B=1024: nrows=512).
        const int ngrp = nrows >> 2;
        const float4* p = fg + (size_t)(r0 + wave) * 64 + lane;
        const int* lp = lab + r0 + wave;
        #pragma unroll 8
        for (int g = 0; g < ngrp; ++g, p += 256, lp += 4) {
            int c = *lp;                 // wave-uniform label
            float4 v = *p;               // coalesced: 1 KB per wave
            if ((unsigned)c < NC) {
                int b0 = c * 64 + lane;  // j=0 slot
                atomicAdd(&acc[b0],                 v.x);
                atomicAdd(&acc[b0 + SQOFF],         v.x * v.x);
                atomicAdd(&acc[b0 + NC * 64],       v.y);
                atomicAdd(&acc[b0 + NC * 64 + SQOFF], v.y * v.y);
                atomicAdd(&acc[b0 + 2 * NC * 64],   v.z);
                atomicAdd(&acc[b0 + 2 * NC * 64 + SQOFF], v.z * v.z);
                atomicAdd(&acc[b0 + 3 * NC * 64],   v.w);
                atomicAdd(&acc[b0 + 3 * NC * 64 + SQOFF], v.w * v.w);
                if (lane == 0) atomicAdd(&acc[CNTOFF + c], 1.0f);
            }
        }
    } else {
        // Generic guarded path (tail blocks).
        const int ngrp = (nrows + 3) >> 2;
        for (int g = 0; g < ngrp; ++g) {
            int r = r0 + g * 4 + wave;
            if (r < r1) {
                int c = lab[r];
                float4 v = fg[(size_t)r * 64 + lane];
                if ((unsigned)c < NC) {
                    int b0 = c * 64 + lane;
                    atomicAdd(&acc[b0],                 v.x);
                    atomicAdd(&acc[b0 + SQOFF],         v.x * v.x);
                    atomicAdd(&acc[b0 + NC * 64],       v.y);
                    atomicAdd(&acc[b0 + NC * 64 + SQOFF], v.y * v.y);
                    atomicAdd(&acc[b0 + 2 * NC * 64],   v.z);
                    atomicAdd(&acc[b0 + 2 * NC * 64 + SQOFF], v.z * v.z);
                    atomicAdd(&acc[b0 + 3 * NC * 64],   v.w);
                    atomicAdd(&acc[b0 + 3 * NC * 64 + SQOFF], v.w * v.w);
                    if (lane == 0) atomicAdd(&acc[CNTOFF + c], 1.0f);
                }
            }
        }
    }
    __syncthreads();

    float* dst = part + (size_t)blockIdx.x * NCELL;
    for (int i = t; i < NCELL; i += 256) dst[i] = acc[i];
}

// ---------------------------------------------------------------------------
// Kernel 2: reduce [B][NCELL] partials along B into [R][NCELL] slices.
// grid = (ceil(NCELL/256), R). Coalesced; layout-agnostic.
// ---------------------------------------------------------------------------
__global__ void k_reduce(const float* __restrict__ part, float* __restrict__ part2,
                         int nb, int bper)
{
    int col = blockIdx.x * 256 + threadIdx.x;
    if (col >= NCELL) return;
    int b0 = blockIdx.y * bper;
    int b1 = min(b0 + bper, nb);
    float s = 0.0f;
    const float* p = part + (size_t)b0 * NCELL + col;
    for (int b = b0; b < b1; ++b, p += NCELL) s += *p;
    part2[(size_t)blockIdx.y * NCELL + col] = s;
}

// ---------------------------------------------------------------------------
// Kernel 3: finish reduction, mean/var, EMA merge, pack [CoV|Mean|Amount].
// grid = (NC), block = (NA). Index remap: col a -> (j = a&3, l = a>>2).
// ---------------------------------------------------------------------------
__global__ void k_final(const float* __restrict__ part2, int nr,
                        const float* __restrict__ Mean, const float* __restrict__ CoV,
                        const float* __restrict__ Amt, float* __restrict__ out)
{
    int c = blockIdx.x;   // 0..18
    int a = threadIdx.x;  // 0..255
    int j = a & 3, l = a >> 2;
    int idx = (j * NC + c) * 64 + l;
    float s = 0.0f, q = 0.0f, cnt = 0.0f;
    for (int i = 0; i < nr; ++i) {
        const float* p = part2 + (size_t)i * NCELL;
        s   += p[idx];
        q   += p[idx + SQOFF];
        cnt += p[CNTOFF + c];   // broadcast
    }
    float amt  = Amt[c];
    float cc   = fmaxf(cnt, 1.0f);
    float mean = s / cc;
    float var  = 0.0f;
    if (cnt > 0.0f) {
        double dv = ((double)q - (double)s * (double)s / (double)cnt) / (double)cnt;
        var = (float)(dv > 0.0 ? dv : 0.0);
    }
    float denom = cnt + amt;
    float w  = (denom != 0.0f) ? (cnt / denom) : 0.0f;  // NaN (0/0) -> 0
    float om = 1.0f - w;
    float mu0 = Mean[c * NA + a];
    float cv0 = CoV[c * NA + a];
    float d   = mu0 - mean;
    float ncv = cv0 * om + var * w + w * om * d * d;
    float nmu = mu0 * om + mean * w;
    out[c * OUTSTRIDE + a]      = ncv;
    out[c * OUTSTRIDE + NA + a] = nmu;
    if (a == 0) out[c * OUTSTRIDE + 2 * NA] = amt + cnt;
}

extern "C" void kernel_launch(void* const* d_in, const int* in_sizes, int n_in,
                              void* d_out, int out_size, void* d_ws, size_t ws_size,
                              hipStream_t stream)
{
    const float* feat = (const float*)d_in[0];
    const int*   lab  = (const int*)d_in[1];
    const float* Mean = (const float*)d_in[2];
    const float* CoV  = (const float*)d_in[3];
    const float* Amt  = (const float*)d_in[4];
    float* out = (float*)d_out;

    const size_t bufBytes = (size_t)NCELL * sizeof(float);
    size_t cap = ws_size / bufBytes;
    int B = 1024, R = 8;               // 4 blocks/CU x 256 CUs
    if (cap < (size_t)(B + R)) {
        if (cap >= 16) { R = 8; B = (int)cap - R; }
        else if (cap >= 2) { R = 1; B = (int)cap - 1; }
        else { R = 1; B = 1; }
    }
    if (R > B) R = B;

    float* part  = (float*)d_ws;
    float* part2 = part + (size_t)B * NCELL;
    int rpb  = (NROW + B - 1) / B;     // 512 for B=1024
    int bper = (B + R - 1) / R;

    hipLaunchKernelGGL(k_accum, dim3(B), dim3(256), 0, stream,
                       feat, lab, part, rpb);
    hipLaunchKernelGGL(k_reduce, dim3((NCELL + 255) / 256, R), dim3(256), 0, stream,
                       part, part2, B, bper);
    hipLaunchKernelGGL(k_final, dim3(NC), dim3(256), 0, stream,
                       part2, R, Mean, CoV, Amt, out);
}